// Round 1
// baseline (14549.686 us; speedup 1.0000x reference)
//
#include <hip/hip_runtime.h>
#include <cstdint>
#include <math.h>

#define GRID_SZ 5
#define SPL_ORD 3
#define IN_FEAT 320
#define OUT_FEAT 2048
#define NB 8              // bases per input feature = GRID_SZ + SPL_ORD
#define KSIL 320          // silu(x) columns
#define KTOT 2880         // 320 silu + 2560 spline-basis columns
#define BM 64
#define BN 64
#define BK 32
#define PAD 68            // LDS row stride in words: 68*4=272 B, 16B-aligned rows
#define BN_EPS 1e-3f

// Evaluate the 8 order-3 B-spline bases exactly as the reference recursion.
// Knots G[u] = (u-3)*0.4f - 1.0f, u = 0..11 (fold to compile-time constants).
__device__ __forceinline__ void bspline8(float x, float* bo) {
    float G[12];
#pragma unroll
    for (int u = 0; u < 12; ++u) G[u] = (float)(u - 3) * 0.4f - 1.0f;
    float b0[11];
#pragma unroll
    for (int u = 0; u < 11; ++u)
        b0[u] = (x >= G[u] && x < G[u + 1]) ? 1.0f : 0.0f;
    float b1[10];
#pragma unroll
    for (int u = 0; u < 10; ++u)
        b1[u] = (x - G[u]) / (G[u + 1] - G[u]) * b0[u]
              + (G[u + 2] - x) / (G[u + 2] - G[u + 1]) * b0[u + 1];
    float b2[9];
#pragma unroll
    for (int u = 0; u < 9; ++u)
        b2[u] = (x - G[u]) / (G[u + 2] - G[u]) * b1[u]
              + (G[u + 3] - x) / (G[u + 3] - G[u + 1]) * b1[u + 1];
#pragma unroll
    for (int u = 0; u < 8; ++u)
        bo[u] = (x - G[u]) / (G[u + 3] - G[u]) * b2[u]
              + (G[u + 4] - x) / (G[u + 4] - G[u + 1]) * b2[u + 1];
}

// Fused: A = [silu(x) | b_splines(x)] generated on the fly into LDS,
// B = [base_weight | spline_weight*scaler] staged per K-chunk,
// epilogue adds the 10-wide linear path, BN (inference), ReLU, writes
// out[n][p][c] with p = blockIdx.y (BN==64 => one point per column-block).
__global__ __launch_bounds__(256)
void pfn_gemm(const float* __restrict__ x, const float* __restrict__ lw,
              const float* __restrict__ bw, const float* __restrict__ sw,
              const float* __restrict__ ss, const float* __restrict__ gamma,
              const float* __restrict__ beta, const float* __restrict__ mean,
              const float* __restrict__ var, float* __restrict__ out, int N) {
    __shared__ float As[BK][PAD];
    __shared__ float Bs[BK][PAD];

    const int tid = threadIdx.x;
    const int bx = blockIdx.x;      // row tile (M)
    const int by = blockIdx.y;      // col tile (== point index p)
    const int row0 = bx * BM;
    const int col0 = by * BN;
    const int tx = tid & 15;        // 16 col-groups of 4
    const int ty = tid >> 4;        // 16 row-groups of 4

    float acc[4][4] = {{0.f, 0.f, 0.f, 0.f}, {0.f, 0.f, 0.f, 0.f},
                       {0.f, 0.f, 0.f, 0.f}, {0.f, 0.f, 0.f, 0.f}};

    for (int kc = 0; kc < KTOT; kc += BK) {
        __syncthreads();
        // ---- stage B tile: combined weight W[o][k] ----
        {
            const int kk = tid & 31;
            const int gk = kc + kk;
            for (int n = (tid >> 5); n < BN; n += 8) {
                const int o = col0 + n;
                float w;
                if (gk < KSIL) {
                    w = bw[o * IN_FEAT + gk];
                } else {
                    const int s = gk - KSIL;
                    const int i = s >> 3, j = s & 7;
                    w = sw[(o * IN_FEAT + i) * NB + j] * ss[o * IN_FEAT + i];
                }
                Bs[kk][n] = w;
            }
        }
        // ---- stage A tile: activations generated on the fly ----
        if (kc < KSIL) {
            const int kk = tid & 31;
            for (int r = (tid >> 5); r < BM; r += 8) {
                const int row = row0 + r;
                float v = 0.0f;
                if (row < N) {
                    const float xv = x[row * IN_FEAT + kc + kk];
                    v = xv / (1.0f + __expf(-xv));
                }
                As[kk][r] = v;
            }
        } else {
            // chunk covers 4 input features x 8 bases; one task per thread
            const int f = tid & 3;
            const int r = tid >> 2;
            const int row = row0 + r;
            const int i0 = (kc - KSIL) >> 3;
            float b[8];
            if (row < N) {
                bspline8(x[row * IN_FEAT + i0 + f], b);
            } else {
#pragma unroll
                for (int j = 0; j < 8; ++j) b[j] = 0.0f;
            }
#pragma unroll
            for (int j = 0; j < 8; ++j) As[f * 8 + j][r] = b[j];
        }
        __syncthreads();
        // ---- FMA inner loop: 4x4 microtile per thread ----
#pragma unroll 8
        for (int kk = 0; kk < BK; ++kk) {
            const float4 av = *(const float4*)&As[kk][ty * 4];
            const float4 bv = *(const float4*)&Bs[kk][tx * 4];
            const float a0[4] = {av.x, av.y, av.z, av.w};
            const float b0[4] = {bv.x, bv.y, bv.z, bv.w};
#pragma unroll
            for (int i = 0; i < 4; ++i)
#pragma unroll
                for (int j = 0; j < 4; ++j)
                    acc[i][j] = fmaf(a0[i], b0[j], acc[i][j]);
        }
    }

    // ---- epilogue: + linear path, BN, ReLU, store x part ----
    const int p = by;  // point index for this whole block
#pragma unroll
    for (int i = 0; i < 4; ++i) {
        const int row = row0 + ty * 4 + i;
        if (row >= N) continue;
        float xq[10];
#pragma unroll
        for (int q = 0; q < 10; ++q) xq[q] = x[row * IN_FEAT + p * 10 + q];
#pragma unroll
        for (int j = 0; j < 4; ++j) {
            const int c = tx * 4 + j;
            float v = acc[i][j];
#pragma unroll
            for (int q = 0; q < 10; ++q) v = fmaf(xq[q], lw[c * 10 + q], v);
            const float inv = rsqrtf(var[c] + BN_EPS);
            v = (v - mean[c]) * (inv * gamma[c]) + beta[c];
            v = fmaxf(v, 0.0f);
            out[((size_t)row * 32 + p) * 128 + c] = v;
        }
    }
}

// Max over the 32 points per (n, c), broadcast into out[n][p][64+c].
__global__ __launch_bounds__(256)
void pfn_maxcat(float* __restrict__ out, int N) {
    const int n = blockIdx.x;
    const int c = threadIdx.x & 63;
    const int g = threadIdx.x >> 6;  // 4 groups over points
    __shared__ float red[4][64];
    float m = 0.0f;  // post-ReLU values are >= 0
    for (int p = g; p < 32; p += 4)
        m = fmaxf(m, out[((size_t)n * 32 + p) * 128 + c]);
    red[g][c] = m;
    __syncthreads();
    m = fmaxf(fmaxf(red[0][c], red[1][c]), fmaxf(red[2][c], red[3][c]));
    for (int p = g; p < 32; p += 4)
        out[((size_t)n * 32 + p) * 128 + 64 + c] = m;
}

extern "C" void kernel_launch(void* const* d_in, const int* in_sizes, int n_in,
                              void* d_out, int out_size, void* d_ws, size_t ws_size,
                              hipStream_t stream) {
    const float* x     = (const float*)d_in[0];  // (N, 32, 10)
    const float* lw    = (const float*)d_in[1];  // (64, 10)
    const float* bw    = (const float*)d_in[2];  // (2048, 320)
    const float* sw    = (const float*)d_in[3];  // (2048, 320, 8)
    const float* ss    = (const float*)d_in[4];  // (2048, 320)
    const float* gamma = (const float*)d_in[5];  // (64,)
    const float* beta  = (const float*)d_in[6];  // (64,)
    const float* mean  = (const float*)d_in[7];  // (64,)
    const float* var   = (const float*)d_in[8];  // (64,)
    float* out = (float*)d_out;                  // (N, 32, 128)

    const int N = in_sizes[0] / IN_FEAT;

    dim3 grid((N + BM - 1) / BM, OUT_FEAT / BN);
    pfn_gemm<<<grid, 256, 0, stream>>>(x, lw, bw, sw, ss, gamma, beta, mean,
                                       var, out, N);
    pfn_maxcat<<<N, 256, 0, stream>>>(out, N);
}

// Round 2
// 3423.600 us; speedup vs baseline: 4.2498x; 4.2498x over previous
//
#include <hip/hip_runtime.h>
#include <cstdint>
#include <math.h>

#define IN_FEAT 320
#define OUT_FEAT 2048
#define NB 8
#define KSIL 320
#define KTOT 2880          // 320 silu + 2560 spline-basis columns
#define BM 128
#define BN 128
#define BK 32
#define LDA 40             // LDS row stride in bf16 elems (80 B, 16B-aligned)
#define BN_EPS 1e-3f

typedef __bf16 bf16;
typedef __attribute__((ext_vector_type(8))) __bf16 bf16x8;
typedef __attribute__((ext_vector_type(4))) float f32x4;

// Uniform cubic B-spline closed form == reference Cox-de Boor recursion.
// Knots G[u] = (u-3)*0.4 - 1, u=0..11. Cell c: G[c] <= x < G[c+1].
// Nonzero bases j = c-3..c with the cardinal cubic weights.
__device__ __forceinline__ void bspline8(float xv, float* b) {
    float xc = (xv + 2.2f) * 2.5f;
    float cf = floorf(xc);
    int c = (int)cf;
    float t = xc - cf;
    float omt = 1.0f - t;
    float t2 = t * t, t3 = t2 * t;
    float w0 = omt * omt * omt * (1.0f / 6.0f);                     // j == c-3
    float w1 = (3.0f * t3 - 6.0f * t2 + 4.0f) * (1.0f / 6.0f);      // j == c-2
    float w2 = (-3.0f * t3 + 3.0f * t2 + 3.0f * t + 1.0f) * (1.0f / 6.0f); // j == c-1
    float w3 = t3 * (1.0f / 6.0f);                                  // j == c
    if (xc < 0.0f) { w0 = w1 = w2 = w3 = 0.0f; }                    // x < -2.2
#pragma unroll
    for (int j = 0; j < 8; ++j) {
        int d = c - j;   // d in {3,2,1,0} selects w0..w3; else 0 (covers x>=2.2 too)
        b[j] = (d == 3) ? w0 : (d == 2) ? w1 : (d == 1) ? w2 : (d == 0) ? w3 : 0.0f;
    }
}

__device__ __forceinline__ bf16x8 pack8(const float* f) {
    bf16x8 v;
#pragma unroll
    for (int j = 0; j < 8; ++j) v[j] = (bf16)f[j];
    return v;
}

// Fuse W = [base_weight | spline_weight*scaler] -> bf16, k-major W[o][2880].
__global__ __launch_bounds__(256) void prep_w(const float* __restrict__ bw,
                                              const float* __restrict__ sw,
                                              const float* __restrict__ ss,
                                              bf16* __restrict__ W) {
    const int k = blockIdx.x * 256 + threadIdx.x;
    const int o = blockIdx.y;
    if (k >= KTOT) return;
    float w;
    if (k < KSIL) {
        w = bw[o * IN_FEAT + k];
    } else {
        const int s = k - KSIL;
        const int i = s >> 3, j = s & 7;
        w = sw[(o * IN_FEAT + i) * NB + j] * ss[o * IN_FEAT + i];
    }
    W[o * KTOT + k] = (bf16)w;
}

template <bool HASW>
__global__ __launch_bounds__(256)
void pfn_gemm(const float* __restrict__ x, const bf16* __restrict__ W,
              const float* __restrict__ bw, const float* __restrict__ sw,
              const float* __restrict__ ss, const float* __restrict__ lw,
              const float* __restrict__ gamma, const float* __restrict__ beta,
              const float* __restrict__ mean, const float* __restrict__ var,
              float* __restrict__ out, int N) {
    __shared__ bf16 As[BM * LDA];
    __shared__ bf16 Bs[BN * LDA];

    const int tid = threadIdx.x;
    const int bx = blockIdx.x;            // row tile over samples
    const int by = blockIdx.y;            // col tile over output features
    const int row0 = bx * BM;
    const int col0 = by * BN;
    const int wave = tid >> 6;
    const int lane = tid & 63;
    const int wr = wave >> 1;             // wave row (0..1), 64 rows each
    const int wc = wave & 1;              // wave col (0..1), 64 cols each
    const int l15 = lane & 15;
    const int quad = lane >> 4;

    f32x4 acc[4][4] = {};

    // ---- staging helpers ----
    auto stage_b = [&](int kc) {
        const int ol = tid >> 1;                  // local col 0..127
        const int k0 = (tid & 1) * 16;
        if (HASW) {
            const bf16x8* src = (const bf16x8*)&W[(size_t)(col0 + ol) * KTOT + kc + k0];
            *(bf16x8*)&Bs[ol * LDA + k0] = src[0];
            *(bf16x8*)&Bs[ol * LDA + k0 + 8] = src[1];
        } else {
            const int o = col0 + ol;
#pragma unroll
            for (int u = 0; u < 16; ++u) {
                const int gk = kc + k0 + u;
                float w;
                if (gk < KSIL) {
                    w = bw[o * IN_FEAT + gk];
                } else {
                    const int s = gk - KSIL;
                    const int i = s >> 3, j = s & 7;
                    w = sw[(o * IN_FEAT + i) * NB + j] * ss[o * IN_FEAT + i];
                }
                Bs[ol * LDA + k0 + u] = (bf16)w;
            }
        }
    };

    auto mma_step = [&]() {
        bf16x8 af[4], bv[4];
#pragma unroll
        for (int i = 0; i < 4; ++i)
            af[i] = *(const bf16x8*)&As[(wr * 64 + i * 16 + l15) * LDA + quad * 8];
#pragma unroll
        for (int j = 0; j < 4; ++j)
            bv[j] = *(const bf16x8*)&Bs[(wc * 64 + j * 16 + l15) * LDA + quad * 8];
#pragma unroll
        for (int i = 0; i < 4; ++i)
#pragma unroll
            for (int j = 0; j < 4; ++j)
                acc[i][j] = __builtin_amdgcn_mfma_f32_16x16x32_bf16(af[i], bv[j],
                                                                   acc[i][j], 0, 0, 0);
    };

    // ---- phase 1: silu columns (10 chunks) ----
    for (int kc = 0; kc < KSIL; kc += BK) {
        __syncthreads();
        stage_b(kc);
        {   // A: silu(x) for 128 rows x 32 cols; 16 elems/thread
            const int r = tid >> 1;
            const int k0 = (tid & 1) * 16;
            const int row = row0 + r;
            float v[16];
            if (row < N) {
                const float* xp = &x[(size_t)row * IN_FEAT + kc + k0];
#pragma unroll
                for (int u = 0; u < 16; ++u) {
                    const float xv = xp[u];
                    v[u] = xv / (1.0f + __expf(-xv));
                }
            } else {
#pragma unroll
                for (int u = 0; u < 16; ++u) v[u] = 0.0f;
            }
            *(bf16x8*)&As[r * LDA + k0] = pack8(v);
            *(bf16x8*)&As[r * LDA + k0 + 8] = pack8(v + 8);
        }
        __syncthreads();
        mma_step();
    }

    // ---- phase 2: spline-basis columns (80 chunks, 4 features x 8 bases each) ----
    for (int kc = KSIL; kc < KTOT; kc += BK) {
        __syncthreads();
        stage_b(kc);
        {
            const int i0 = (kc - KSIL) >> 3;      // first feature of this chunk
#pragma unroll
            for (int s = 0; s < 2; ++s) {
                const int task = tid + s * 256;    // 512 tasks: 128 rows x 4 features
                const int r = task >> 2;
                const int f = task & 3;
                const int row = row0 + r;
                float b[8];
                if (row < N) {
                    bspline8(x[(size_t)row * IN_FEAT + i0 + f], b);
                } else {
#pragma unroll
                    for (int j = 0; j < 8; ++j) b[j] = 0.0f;
                }
                *(bf16x8*)&As[r * LDA + f * 8] = pack8(b);
            }
        }
        __syncthreads();
        mma_step();
    }

    // ---- epilogue: + linear path, BN, ReLU, store ----
    const int p = by * 2 + wc;                    // point index, uniform per wave
    float sc[4], sh[4];                           // BN scale/shift per j (c = j*16+l15)
#pragma unroll
    for (int j = 0; j < 4; ++j) {
        const int c = j * 16 + l15;
        const float s = rsqrtf(var[c] + BN_EPS) * gamma[c];
        sc[j] = s;
        sh[j] = beta[c] - mean[c] * s;
    }
#pragma unroll
    for (int i = 0; i < 4; ++i) {
#pragma unroll
        for (int reg = 0; reg < 4; ++reg) {
            const int row = row0 + wr * 64 + i * 16 + quad * 4 + reg;
            if (row >= N) continue;
            float xq[10];
            const float* xp = &x[(size_t)row * IN_FEAT + p * 10];
#pragma unroll
            for (int q = 0; q < 10; ++q) xq[q] = xp[q];
#pragma unroll
            for (int j = 0; j < 4; ++j) {
                const int c = j * 16 + l15;
                float v = acc[i][j][reg];
#pragma unroll
                for (int q = 0; q < 10; ++q) v = fmaf(xq[q], lw[c * 10 + q], v);
                v = fmaxf(v * sc[j] + sh[j], 0.0f);
                out[((size_t)row * 32 + p) * 128 + c] = v;
            }
        }
    }
}

// Max over the 32 points per (n, c), broadcast into out[n][p][64+c].
__global__ __launch_bounds__(256) void pfn_maxcat(float* __restrict__ out, int N) {
    const int n = blockIdx.x;
    const int c = threadIdx.x & 63;
    const int g = threadIdx.x >> 6;
    __shared__ float red[4][64];
    float m = 0.0f;  // post-ReLU values are >= 0
    for (int pp = g; pp < 32; pp += 4)
        m = fmaxf(m, out[((size_t)n * 32 + pp) * 128 + c]);
    red[g][c] = m;
    __syncthreads();
    m = fmaxf(fmaxf(red[0][c], red[1][c]), fmaxf(red[2][c], red[3][c]));
    for (int pp = g; pp < 32; pp += 4)
        out[((size_t)n * 32 + pp) * 128 + 64 + c] = m;
}

extern "C" void kernel_launch(void* const* d_in, const int* in_sizes, int n_in,
                              void* d_out, int out_size, void* d_ws, size_t ws_size,
                              hipStream_t stream) {
    const float* x     = (const float*)d_in[0];  // (N, 32, 10)
    const float* lw    = (const float*)d_in[1];  // (64, 10)
    const float* bw    = (const float*)d_in[2];  // (2048, 320)
    const float* sw    = (const float*)d_in[3];  // (2048, 320, 8)
    const float* ss    = (const float*)d_in[4];  // (2048, 320)
    const float* gamma = (const float*)d_in[5];
    const float* beta  = (const float*)d_in[6];
    const float* mean  = (const float*)d_in[7];
    const float* var   = (const float*)d_in[8];
    float* out = (float*)d_out;                  // (N, 32, 128)

    const int N = in_sizes[0] / IN_FEAT;
    const size_t w_bytes = (size_t)OUT_FEAT * KTOT * sizeof(bf16);
    const bool hasW = ws_size >= w_bytes;

    dim3 grid((N + BM - 1) / BM, OUT_FEAT / BN);  // bx fastest: W slab stays L2-hot
    if (hasW) {
        bf16* W = (bf16*)d_ws;
        prep_w<<<dim3((KTOT + 255) / 256, OUT_FEAT), 256, 0, stream>>>(bw, sw, ss, W);
        pfn_gemm<true><<<grid, 256, 0, stream>>>(x, W, bw, sw, ss, lw, gamma, beta,
                                                 mean, var, out, N);
    } else {
        pfn_gemm<false><<<grid, 256, 0, stream>>>(x, nullptr, bw, sw, ss, lw, gamma,
                                                  beta, mean, var, out, N);
    }
    pfn_maxcat<<<N, 256, 0, stream>>>(out, N);
}

// Round 3
// 1697.641 us; speedup vs baseline: 8.5705x; 2.0167x over previous
//
#include <hip/hip_runtime.h>
#include <cstdint>
#include <math.h>

#define IN_FEAT 320
#define OUT_FEAT 2048
#define NB 8
#define KSIL 320
#define KTOT 2880          // 320 silu + 2560 spline-basis columns
#define BM 128
#define BN 128
#define BK 32
#define LDA 40             // tier-2 fallback LDS stride
#define BN_EPS 1e-3f
#define A_OFF ((size_t)16 << 20)   // A starts 16 MB into d_ws (W lives below)

typedef __bf16 bf16;
typedef __attribute__((ext_vector_type(8))) __bf16 bf16x8;
typedef __attribute__((ext_vector_type(4))) float f32x4;

// Uniform cubic B-spline closed form == reference Cox-de Boor recursion.
__device__ __forceinline__ void bspline8(float xv, float* b) {
    float xc = (xv + 2.2f) * 2.5f;
    float cf = floorf(xc);
    int c = (int)cf;
    float t = xc - cf;
    float omt = 1.0f - t;
    float t2 = t * t, t3 = t2 * t;
    float w0 = omt * omt * omt * (1.0f / 6.0f);
    float w1 = (3.0f * t3 - 6.0f * t2 + 4.0f) * (1.0f / 6.0f);
    float w2 = (-3.0f * t3 + 3.0f * t2 + 3.0f * t + 1.0f) * (1.0f / 6.0f);
    float w3 = t3 * (1.0f / 6.0f);
    if (xc < 0.0f) { w0 = w1 = w2 = w3 = 0.0f; }
#pragma unroll
    for (int j = 0; j < 8; ++j) {
        int d = c - j;
        b[j] = (d == 3) ? w0 : (d == 2) ? w1 : (d == 1) ? w2 : (d == 0) ? w3 : 0.0f;
    }
}

__device__ __forceinline__ bf16x8 pack8(const float* f) {
    bf16x8 v;
#pragma unroll
    for (int j = 0; j < 8; ++j) v[j] = (bf16)f[j];
    return v;
}

__device__ __forceinline__ void gl2lds16(const bf16* g, bf16* l) {
    __builtin_amdgcn_global_load_lds(
        (const __attribute__((address_space(1))) void*)g,
        (__attribute__((address_space(3))) void*)l, 16, 0, 0);
}

// Fuse W = [base_weight | spline_weight*scaler] -> bf16, k-major W[o][2880].
__global__ __launch_bounds__(256) void prep_w(const float* __restrict__ bw,
                                              const float* __restrict__ sw,
                                              const float* __restrict__ ss,
                                              bf16* __restrict__ W) {
    const int k = blockIdx.x * 256 + threadIdx.x;
    const int o = blockIdx.y;
    if (k >= KTOT) return;
    float w;
    if (k < KSIL) {
        w = bw[o * IN_FEAT + k];
    } else {
        const int s = k - KSIL;
        const int i = s >> 3, j = s & 7;
        w = sw[(o * IN_FEAT + i) * NB + j] * ss[o * IN_FEAT + i];
    }
    W[o * KTOT + k] = (bf16)w;
}

// Precompute A = [silu(x) | bases(x)] bf16, k-major A[row][2880].
__global__ __launch_bounds__(256) void prep_a(const float* __restrict__ x,
                                              bf16* __restrict__ A, int total) {
    const int t = blockIdx.x * 256 + threadIdx.x;
    if (t >= total) return;
    const int row = t / IN_FEAT;
    const int f = t - row * IN_FEAT;
    const float xv = x[t];
    A[(size_t)row * KTOT + f] = (bf16)(xv / (1.0f + __expf(-xv)));
    float b[8];
    bspline8(xv, b);
    *(bf16x8*)&A[(size_t)row * KTOT + KSIL + f * 8] = pack8(b);
}

// Tier-1: pure GEMM from precomputed A (ws) and W (ws), global_load_lds
// staging with XOR-swizzled LDS layout, fused linear-path/BN/ReLU epilogue.
__global__ __launch_bounds__(256)
void pfn_gemm_ws(const float* __restrict__ x, const bf16* __restrict__ A,
                 const bf16* __restrict__ W, const float* __restrict__ lw,
                 const float* __restrict__ gamma, const float* __restrict__ beta,
                 const float* __restrict__ mean, const float* __restrict__ var,
                 float* __restrict__ out, int N, int nbx) {
    __shared__ bf16 As[BM * BK];
    __shared__ bf16 Bs[BN * BK];

    // super-tile remap: 32 bx-tiles x 16 by-tiles per group (A slab L3-hot)
    const int blk = blockIdx.x;
    const int sid = blk >> 9;
    const int t = blk & 511;
    const int by = t >> 5;
    const int bx = (sid << 5) + (t & 31);
    if (bx >= nbx) return;

    const int row0 = bx * BM;
    const int col0 = by * BN;
    const int tid = threadIdx.x;
    const int wave = tid >> 6;
    const int lane = tid & 63;
    const int wr = wave >> 1;
    const int wc = wave & 1;
    const int l15 = lane & 15;
    const int quad = lane >> 4;

    // staging: thread owns 16-B chunks tid and tid+256 of each tile.
    // chunk q -> LDS byte q*16, holds row r=q>>2, k-group g = (q&3)^((r>>1)&3)
    const int r0 = tid >> 2;
    const int s0 = tid & 3;
    const int g0 = s0 ^ ((r0 >> 1) & 3);
    const bf16* a0 = A + (size_t)(row0 + r0) * KTOT + g0 * 8;
    const bf16* a1 = a0 + (size_t)64 * KTOT;
    const bf16* b0 = W + (size_t)(col0 + r0) * KTOT + g0 * 8;
    const bf16* b1 = b0 + (size_t)64 * KTOT;
    bf16* lA0 = As + tid * 8;
    bf16* lA1 = As + (tid + 256) * 8;
    bf16* lB0 = Bs + tid * 8;
    bf16* lB1 = Bs + (tid + 256) * 8;

    // fragment-read swizzle slot (same formula: row low bits == l15 low bits)
    const int sfr = quad ^ ((l15 >> 1) & 3);

    f32x4 acc[4][4] = {};

    for (int kc = 0; kc < KTOT; kc += BK) {
        __syncthreads();
        gl2lds16(a0 + kc, lA0);
        gl2lds16(a1 + kc, lA1);
        gl2lds16(b0 + kc, lB0);
        gl2lds16(b1 + kc, lB1);
        __syncthreads();
        bf16x8 af[4], bv[4];
#pragma unroll
        for (int i = 0; i < 4; ++i)
            af[i] = *(const bf16x8*)&As[(wr * 64 + i * 16 + l15) * BK + sfr * 8];
#pragma unroll
        for (int j = 0; j < 4; ++j)
            bv[j] = *(const bf16x8*)&Bs[(wc * 64 + j * 16 + l15) * BK + sfr * 8];
#pragma unroll
        for (int i = 0; i < 4; ++i)
#pragma unroll
            for (int j = 0; j < 4; ++j)
                acc[i][j] = __builtin_amdgcn_mfma_f32_16x16x32_bf16(af[i], bv[j],
                                                                   acc[i][j], 0, 0, 0);
    }

    // epilogue: + linear path, BN, ReLU, store
    const int p = by * 2 + wc;
    float sc[4], sh[4];
#pragma unroll
    for (int j = 0; j < 4; ++j) {
        const int c = j * 16 + l15;
        const float s = rsqrtf(var[c] + BN_EPS) * gamma[c];
        sc[j] = s;
        sh[j] = beta[c] - mean[c] * s;
    }
#pragma unroll
    for (int i = 0; i < 4; ++i) {
#pragma unroll
        for (int reg = 0; reg < 4; ++reg) {
            const int row = row0 + wr * 64 + i * 16 + quad * 4 + reg;
            if (row >= N) continue;
            float xq[10];
            const float* xp = &x[(size_t)row * IN_FEAT + p * 10];
#pragma unroll
            for (int q = 0; q < 10; ++q) xq[q] = xp[q];
#pragma unroll
            for (int j = 0; j < 4; ++j) {
                const int c = j * 16 + l15;
                float v = acc[i][j][reg];
#pragma unroll
                for (int q = 0; q < 10; ++q) v = fmaf(xq[q], lw[c * 10 + q], v);
                v = fmaxf(v * sc[j] + sh[j], 0.0f);
                out[((size_t)row * 32 + p) * 128 + c] = v;
            }
        }
    }
}

// ---- Tier-2/0 fallback: round-2 fused kernel (known-correct) ----
template <bool HASW>
__global__ __launch_bounds__(256)
void pfn_gemm(const float* __restrict__ x, const bf16* __restrict__ W,
              const float* __restrict__ bw, const float* __restrict__ sw,
              const float* __restrict__ ss, const float* __restrict__ lw,
              const float* __restrict__ gamma, const float* __restrict__ beta,
              const float* __restrict__ mean, const float* __restrict__ var,
              float* __restrict__ out, int N) {
    __shared__ bf16 As[BM * LDA];
    __shared__ bf16 Bs[BN * LDA];
    const int tid = threadIdx.x;
    const int row0 = blockIdx.x * BM;
    const int col0 = blockIdx.y * BN;
    const int wave = tid >> 6;
    const int lane = tid & 63;
    const int wr = wave >> 1;
    const int wc = wave & 1;
    const int l15 = lane & 15;
    const int quad = lane >> 4;
    f32x4 acc[4][4] = {};
    auto stage_b = [&](int kc) {
        const int ol = tid >> 1;
        const int k0 = (tid & 1) * 16;
        if (HASW) {
            const bf16x8* src = (const bf16x8*)&W[(size_t)(col0 + ol) * KTOT + kc + k0];
            *(bf16x8*)&Bs[ol * LDA + k0] = src[0];
            *(bf16x8*)&Bs[ol * LDA + k0 + 8] = src[1];
        } else {
            const int o = col0 + ol;
#pragma unroll
            for (int u = 0; u < 16; ++u) {
                const int gk = kc + k0 + u;
                float w;
                if (gk < KSIL) {
                    w = bw[o * IN_FEAT + gk];
                } else {
                    const int s = gk - KSIL;
                    const int i = s >> 3, j = s & 7;
                    w = sw[(o * IN_FEAT + i) * NB + j] * ss[o * IN_FEAT + i];
                }
                Bs[ol * LDA + k0 + u] = (bf16)w;
            }
        }
    };
    auto mma_step = [&]() {
        bf16x8 af[4], bv[4];
#pragma unroll
        for (int i = 0; i < 4; ++i)
            af[i] = *(const bf16x8*)&As[(wr * 64 + i * 16 + l15) * LDA + quad * 8];
#pragma unroll
        for (int j = 0; j < 4; ++j)
            bv[j] = *(const bf16x8*)&Bs[(wc * 64 + j * 16 + l15) * LDA + quad * 8];
#pragma unroll
        for (int i = 0; i < 4; ++i)
#pragma unroll
            for (int j = 0; j < 4; ++j)
                acc[i][j] = __builtin_amdgcn_mfma_f32_16x16x32_bf16(af[i], bv[j],
                                                                   acc[i][j], 0, 0, 0);
    };
    for (int kc = 0; kc < KSIL; kc += BK) {
        __syncthreads();
        stage_b(kc);
        {
            const int r = tid >> 1;
            const int k0 = (tid & 1) * 16;
            const int row = row0 + r;
            float v[16];
            if (row < N) {
                const float* xp = &x[(size_t)row * IN_FEAT + kc + k0];
#pragma unroll
                for (int u = 0; u < 16; ++u) {
                    const float xv = xp[u];
                    v[u] = xv / (1.0f + __expf(-xv));
                }
            } else {
#pragma unroll
                for (int u = 0; u < 16; ++u) v[u] = 0.0f;
            }
            *(bf16x8*)&As[r * LDA + k0] = pack8(v);
            *(bf16x8*)&As[r * LDA + k0 + 8] = pack8(v + 8);
        }
        __syncthreads();
        mma_step();
    }
    for (int kc = KSIL; kc < KTOT; kc += BK) {
        __syncthreads();
        stage_b(kc);
        {
            const int i0 = (kc - KSIL) >> 3;
#pragma unroll
            for (int s = 0; s < 2; ++s) {
                const int task = tid + s * 256;
                const int r = task >> 2;
                const int f = task & 3;
                const int row = row0 + r;
                float b[8];
                if (row < N) {
                    bspline8(x[(size_t)row * IN_FEAT + i0 + f], b);
                } else {
#pragma unroll
                    for (int j = 0; j < 8; ++j) b[j] = 0.0f;
                }
                *(bf16x8*)&As[r * LDA + f * 8] = pack8(b);
            }
        }
        __syncthreads();
        mma_step();
    }
    const int p = blockIdx.y * 2 + wc;
    float sc[4], sh[4];
#pragma unroll
    for (int j = 0; j < 4; ++j) {
        const int c = j * 16 + l15;
        const float s = rsqrtf(var[c] + BN_EPS) * gamma[c];
        sc[j] = s;
        sh[j] = beta[c] - mean[c] * s;
    }
#pragma unroll
    for (int i = 0; i < 4; ++i) {
#pragma unroll
        for (int reg = 0; reg < 4; ++reg) {
            const int row = row0 + wr * 64 + i * 16 + quad * 4 + reg;
            if (row >= N) continue;
            float xq[10];
            const float* xp = &x[(size_t)row * IN_FEAT + p * 10];
#pragma unroll
            for (int q = 0; q < 10; ++q) xq[q] = xp[q];
#pragma unroll
            for (int j = 0; j < 4; ++j) {
                const int c = j * 16 + l15;
                float v = acc[i][j][reg];
#pragma unroll
                for (int q = 0; q < 10; ++q) v = fmaf(xq[q], lw[c * 10 + q], v);
                v = fmaxf(v * sc[j] + sh[j], 0.0f);
                out[((size_t)row * 32 + p) * 128 + c] = v;
            }
        }
    }
}

// Max over the 32 points per (n, c), broadcast into out[n][p][64+c].
__global__ __launch_bounds__(256) void pfn_maxcat(float* __restrict__ out, int N) {
    const int n = blockIdx.x;
    const int c = threadIdx.x & 63;
    const int g = threadIdx.x >> 6;
    __shared__ float red[4][64];
    float m = 0.0f;
    for (int pp = g; pp < 32; pp += 4)
        m = fmaxf(m, out[((size_t)n * 32 + pp) * 128 + c]);
    red[g][c] = m;
    __syncthreads();
    m = fmaxf(fmaxf(red[0][c], red[1][c]), fmaxf(red[2][c], red[3][c]));
    for (int pp = g; pp < 32; pp += 4)
        out[((size_t)n * 32 + pp) * 128 + 64 + c] = m;
}

extern "C" void kernel_launch(void* const* d_in, const int* in_sizes, int n_in,
                              void* d_out, int out_size, void* d_ws, size_t ws_size,
                              hipStream_t stream) {
    const float* x     = (const float*)d_in[0];
    const float* lw    = (const float*)d_in[1];
    const float* bw    = (const float*)d_in[2];
    const float* sw    = (const float*)d_in[3];
    const float* ss    = (const float*)d_in[4];
    const float* gamma = (const float*)d_in[5];
    const float* beta  = (const float*)d_in[6];
    const float* mean  = (const float*)d_in[7];
    const float* var   = (const float*)d_in[8];
    float* out = (float*)d_out;

    const int N = in_sizes[0] / IN_FEAT;
    const int nbx = (N + BM - 1) / BM;
    const size_t w_bytes = (size_t)OUT_FEAT * KTOT * sizeof(bf16);
    const size_t a_bytes = (size_t)nbx * BM * KTOT * sizeof(bf16);

    if (ws_size >= A_OFF + a_bytes) {
        bf16* W = (bf16*)d_ws;
        bf16* A = (bf16*)((char*)d_ws + A_OFF);
        prep_w<<<dim3((KTOT + 255) / 256, OUT_FEAT), 256, 0, stream>>>(bw, sw, ss, W);
        prep_a<<<(N * IN_FEAT + 255) / 256, 256, 0, stream>>>(x, A, N * IN_FEAT);
        const int supers = (nbx + 31) / 32;
        pfn_gemm_ws<<<supers * 512, 256, 0, stream>>>(x, A, W, lw, gamma, beta,
                                                      mean, var, out, N, nbx);
    } else if (ws_size >= w_bytes) {
        bf16* W = (bf16*)d_ws;
        prep_w<<<dim3((KTOT + 255) / 256, OUT_FEAT), 256, 0, stream>>>(bw, sw, ss, W);
        pfn_gemm<true><<<dim3(nbx, OUT_FEAT / BN), 256, 0, stream>>>(
            x, W, bw, sw, ss, lw, gamma, beta, mean, var, out, N);
    } else {
        pfn_gemm<false><<<dim3(nbx, OUT_FEAT / BN), 256, 0, stream>>>(
            x, nullptr, bw, sw, ss, lw, gamma, beta, mean, var, out, N);
    }
    pfn_maxcat<<<N, 256, 0, stream>>>(out, N);
}